// Round 1
// baseline (3177.055 us; speedup 1.0000x reference)
//
#include <hip/hip_runtime.h>
#include <math.h>

// Problem constants (from reference setup_inputs)
#define BQ 2048      // queries
#define DD 768       // dim
#define NPASS 8      // n_passages
#define PP 16384     // passages = BQ*NPASS
#define NCHUNK 8     // passage chunks (parallelism over passage axis)
#define CHUNK 2048   // PP / NCHUNK
#define TM 16        // query tile
#define TN 64        // passage tile
#define TK 96        // k tile
#define NTILE 32     // CHUNK / TN
#define NKT 8        // DD / TK

#define ALPHA_C 2.6f
#define INV_2SIG2 (1.0f / 6.48f)   // 1/(2*1.8^2)

// ---------------------------------------------------------------------------
// Kernel 1: s_t[i] = dot(q[i], p[i*NPASS])  — one wave per query
// ---------------------------------------------------------------------------
__global__ __launch_bounds__(256) void st_kernel(const float* __restrict__ q,
                                                 const float* __restrict__ p,
                                                 float* __restrict__ st) {
  const int wv = threadIdx.x >> 6;
  const int lane = threadIdx.x & 63;
  const int qi = blockIdx.x * 4 + wv;
  const float4* q4 = (const float4*)(q + (size_t)qi * DD);
  const float4* p4 = (const float4*)(p + (size_t)qi * NPASS * DD);
  float acc = 0.f;
#pragma unroll
  for (int u = 0; u < 3; ++u) {   // 192 float4 per row = 64 lanes * 3
    float4 a = q4[lane + 64 * u];
    float4 b = p4[lane + 64 * u];
    acc = fmaf(a.x, b.x, acc);
    acc = fmaf(a.y, b.y, acc);
    acc = fmaf(a.z, b.z, acc);
    acc = fmaf(a.w, b.w, acc);
  }
#pragma unroll
  for (int off = 32; off >= 1; off >>= 1) acc += __shfl_xor(acc, off);
  if (lane == 0) st[qi] = acc;
}

// ---------------------------------------------------------------------------
// Kernel 2: fused score GEMM + online softmax stats + rank count (partials).
// Block = 256 threads (4 waves). blockIdx.x = query tile (TM queries),
// blockIdx.y = passage chunk. Wave w owns queries [w*4, w*4+4); lane = passage
// column within the TN tile. Per-wave online (m, l, cnt) kept replicated in
// all lanes (ballot/butterfly leave identical values lane-wide).
// ---------------------------------------------------------------------------
__global__ __launch_bounds__(256) void score_kernel(const float* __restrict__ q,
                                                    const float* __restrict__ p,
                                                    const float* __restrict__ st,
                                                    float* __restrict__ pm,
                                                    float* __restrict__ pl,
                                                    float* __restrict__ pc) {
  __shared__ float Qs[TM * TK];      // 16x96 floats, row stride 96 (16B-aligned)
  __shared__ float Ps[TN][TK + 1];   // 64x97: pad 1 -> conflict-free Ps[col][kk]
  __shared__ float Sst[TM];

  const int t = threadIdx.x;
  const int col = t & 63;
  const int wv = t >> 6;
  const int qbase = blockIdx.x * TM;
  const int chunk = blockIdx.y;

  if (t < TM) Sst[t] = st[qbase + t];

  float m_run[4] = {-1e30f, -1e30f, -1e30f, -1e30f};
  float l_run[4] = {0.f, 0.f, 0.f, 0.f};
  float cnt[4] = {0.f, 0.f, 0.f, 0.f};

  const float4* q4g = (const float4*)q;
  const float4* p4g = (const float4*)p;
  float4* Qs4 = (float4*)Qs;

  for (int tile = 0; tile < NTILE; ++tile) {
    const int j0 = chunk * CHUNK + tile * TN;
    float c0 = 0.f, c1 = 0.f, c2 = 0.f, c3 = 0.f;

    for (int kt = 0; kt < NKT; ++kt) {
      // ---- stage Q tile: 16x96 floats = 384 float4 ----
      {
        int id = t;
#pragma unroll
        for (int u = 0; u < 2; ++u) {
          if (id < 384) {
            int m = id / 24;        // 24 float4 per row of 96
            int kq = id % 24;
            Qs4[m * 24 + kq] = q4g[(size_t)(qbase + m) * 192 + kt * 24 + kq];
          }
          id += 256;
        }
      }
      // ---- stage P tile transposed to Ps[passage][k]: 64x96 = 1536 float4 ----
      {
#pragma unroll
        for (int u = 0; u < 6; ++u) {
          int id = t + 256 * u;     // 0..1535
          int j = id / 24;          // passage within tile
          int kq = id % 24;
          float4 v = p4g[(size_t)(j0 + j) * 192 + kt * 24 + kq];
          int k = kq * 4;
          Ps[j][k + 0] = v.x;
          Ps[j][k + 1] = v.y;
          Ps[j][k + 2] = v.z;
          Ps[j][k + 3] = v.w;
        }
      }
      __syncthreads();
      // ---- compute: c[r] += Q[wv*4+r][k] * P[col][k] over TK ----
#pragma unroll
      for (int kk = 0; kk < TK; kk += 4) {
        float4 a0 = *(const float4*)&Qs[(wv * 4 + 0) * TK + kk];  // wave-uniform broadcast
        float4 a1 = *(const float4*)&Qs[(wv * 4 + 1) * TK + kk];
        float4 a2 = *(const float4*)&Qs[(wv * 4 + 2) * TK + kk];
        float4 a3 = *(const float4*)&Qs[(wv * 4 + 3) * TK + kk];
        float b0 = Ps[col][kk + 0];   // conflict-free (pad 97)
        float b1 = Ps[col][kk + 1];
        float b2 = Ps[col][kk + 2];
        float b3 = Ps[col][kk + 3];
        c0 = fmaf(a0.x, b0, c0); c0 = fmaf(a0.y, b1, c0); c0 = fmaf(a0.z, b2, c0); c0 = fmaf(a0.w, b3, c0);
        c1 = fmaf(a1.x, b0, c1); c1 = fmaf(a1.y, b1, c1); c1 = fmaf(a1.z, b2, c1); c1 = fmaf(a1.w, b3, c1);
        c2 = fmaf(a2.x, b0, c2); c2 = fmaf(a2.y, b1, c2); c2 = fmaf(a2.z, b2, c2); c2 = fmaf(a2.w, b3, c2);
        c3 = fmaf(a3.x, b0, c3); c3 = fmaf(a3.y, b1, c3); c3 = fmaf(a3.z, b2, c3); c3 = fmaf(a3.w, b3, c3);
      }
      __syncthreads();
    }

    // ---- epilogue: online softmax + rank-count update for this TN tile ----
    float cs[4] = {c0, c1, c2, c3};
#pragma unroll
    for (int r = 0; r < 4; ++r) {
      const int m = wv * 4 + r;
      const float s = cs[r];
      const int jg = j0 + col;
      const int tq = (qbase + m) * NPASS;
      const bool pred = (s > Sst[m]) && (jg != tq);  // exclude self; ties ~measure-zero
      unsigned long long bal = __ballot(pred ? 1 : 0);
      cnt[r] += (float)__popcll(bal);
      float mt = s;
#pragma unroll
      for (int off = 32; off >= 1; off >>= 1) mt = fmaxf(mt, __shfl_xor(mt, off));
      const float mn = fmaxf(m_run[r], mt);
      float e = __expf(s - mn);
#pragma unroll
      for (int off = 32; off >= 1; off >>= 1) e += __shfl_xor(e, off);
      l_run[r] = l_run[r] * __expf(m_run[r] - mn) + e;
      m_run[r] = mn;
    }
  }

  if (col == 0) {
#pragma unroll
    for (int r = 0; r < 4; ++r) {
      const int qi = qbase + wv * 4 + r;
      const int idx = qi * NCHUNK + chunk;
      pm[idx] = m_run[r];
      pl[idx] = l_run[r];
      pc[idx] = cnt[r];
    }
  }
}

// ---------------------------------------------------------------------------
// Kernel 3: merge chunk partials per query, weighted CE, mean -> atomicAdd.
// ---------------------------------------------------------------------------
__global__ __launch_bounds__(256) void finalize_kernel(const float* __restrict__ st,
                                                       const float* __restrict__ pm,
                                                       const float* __restrict__ pl,
                                                       const float* __restrict__ pc,
                                                       float* __restrict__ out) {
  const int qi = blockIdx.x * 256 + threadIdx.x;
  float mg = -1e30f;
#pragma unroll
  for (int c = 0; c < NCHUNK; ++c) mg = fmaxf(mg, pm[qi * NCHUNK + c]);
  float lg = 0.f, cntf = 0.f;
#pragma unroll
  for (int c = 0; c < NCHUNK; ++c) {
    lg += pl[qi * NCHUNK + c] * __expf(pm[qi * NCHUNK + c] - mg);
    cntf += pc[qi * NCHUNK + c];
  }
  const float raw = logf(lg) + mg - st[qi];   // -log_softmax[target]
  const float dr = cntf - 1.0f;               // rank - OPTIMAL_RANK
  const float w = 1.0f + ALPHA_C * __expf(-(dr * dr) * INV_2SIG2);
  float loss = raw * w * (1.0f / (float)BQ);
#pragma unroll
  for (int off = 32; off >= 1; off >>= 1) loss += __shfl_xor(loss, off);
  __shared__ float red[4];
  if ((threadIdx.x & 63) == 0) red[threadIdx.x >> 6] = loss;
  __syncthreads();
  if (threadIdx.x == 0) atomicAdd(out, red[0] + red[1] + red[2] + red[3]);
}

// ---------------------------------------------------------------------------
extern "C" void kernel_launch(void* const* d_in, const int* in_sizes, int n_in,
                              void* d_out, int out_size, void* d_ws, size_t ws_size,
                              hipStream_t stream) {
  const float* q = (const float*)d_in[0];
  const float* p = (const float*)d_in[1];
  float* ws = (float*)d_ws;
  float* st = ws;                      // BQ floats
  float* pm = ws + BQ;                 // BQ*NCHUNK
  float* pl = pm + BQ * NCHUNK;        // BQ*NCHUNK
  float* pc = pl + BQ * NCHUNK;        // BQ*NCHUNK  (total ~200 KB of ws)
  float* out = (float*)d_out;

  hipMemsetAsync(out, 0, sizeof(float), stream);  // d_out is poisoned 0xAA

  st_kernel<<<BQ / 4, 256, 0, stream>>>(q, p, st);

  dim3 g2(BQ / TM, NCHUNK);
  score_kernel<<<g2, 256, 0, stream>>>(q, p, st, pm, pl, pc);

  finalize_kernel<<<NCHUNK, 256, 0, stream>>>(st, pm, pl, pc, out);
}

// Round 2
// 224.856 us; speedup vs baseline: 14.1293x; 14.1293x over previous
//
#include <hip/hip_runtime.h>
#include <math.h>

// Problem: scores = q[2048x768] @ p[16384x768]^T (fp32 in), per-query
// rank-of-target + log-softmax CE + Gaussian rank weight -> mean (scalar).
// Strategy: bf16-cast + MFMA 16x16x32 GEMM (m97 structure), fused epilogue.

#define BQ 2048
#define DD 768
#define NPASS 8
#define PP 16384
#define BM 128
#define BN 128
#define BK 64
#define KITERS 12          // 768/64
#define NBLK (PP/BN)       // 128 n-blocks
#define MBLK (BQ/BM)       // 16 m-blocks
#define NCHUNKS (NBLK*2)   // 256 partial chunks per query (2 wv_n per block)

#define ALPHA_C 2.6f
#define INV_2SIG2 (1.0f/6.48f)   // 1/(2*1.8^2)

typedef __attribute__((ext_vector_type(8))) short short8;   // 8 bf16 (4 VGPRs)
typedef __attribute__((ext_vector_type(4))) float floatx4;  // MFMA C/D

__device__ __forceinline__ unsigned short f2b(float f) {  // fp32 -> bf16 RNE
  union { float f; unsigned u; } c; c.f = f;
  unsigned u = c.u;
  return (unsigned short)((u + 0x7fffu + ((u >> 16) & 1u)) >> 16);
}
__device__ __forceinline__ float b2f(unsigned short b) {
  union { unsigned u; float f; } c; c.u = ((unsigned)b) << 16;
  return c.f;
}
__device__ __forceinline__ float dot2(unsigned ua, unsigned ub, float acc) {
  acc = fmaf(b2f((unsigned short)(ua & 0xffffu)), b2f((unsigned short)(ub & 0xffffu)), acc);
  acc = fmaf(b2f((unsigned short)(ua >> 16)), b2f((unsigned short)(ub >> 16)), acc);
  return acc;
}

// ---------------------------------------------------------------------------
// Kernel 1: cast q and p to bf16 (vectorized: float4 in, 4 bf16 out)
// ---------------------------------------------------------------------------
#define NQ4   393216     // 2048*768/4
#define NTOT4 3538944    // (2048+16384)*768/4
__global__ __launch_bounds__(256) void cast_kernel(const float4* __restrict__ q,
                                                   const float4* __restrict__ p,
                                                   uint2* __restrict__ qb,
                                                   uint2* __restrict__ pb) {
  int i = blockIdx.x * 256 + threadIdx.x;
  float4 v; uint2* o;
  if (i < NQ4) { v = q[i]; o = qb + i; }
  else         { v = p[i - NQ4]; o = pb + (i - NQ4); }
  uint2 w;
  w.x = (unsigned)f2b(v.x) | ((unsigned)f2b(v.y) << 16);
  w.y = (unsigned)f2b(v.z) | ((unsigned)f2b(v.w) << 16);
  *o = w;
}

// ---------------------------------------------------------------------------
// Kernel 2: s_t[i] = dot(qb[i], pb[i*NPASS]) in fp32 (bf16 inputs) — 1 wave/query
// ---------------------------------------------------------------------------
__global__ __launch_bounds__(256) void st_kernel(const unsigned short* __restrict__ qb,
                                                 const unsigned short* __restrict__ pb,
                                                 float* __restrict__ st) {
  const int wv = threadIdx.x >> 6, lane = threadIdx.x & 63;
  const int qi = blockIdx.x * 4 + wv;
  const unsigned short* a = qb + (size_t)qi * DD;
  const unsigned short* b = pb + (size_t)qi * NPASS * DD;
  float acc = 0.f;
  uint4 a4 = ((const uint4*)a)[lane];          // elements [lane*8, lane*8+8)
  uint4 b4 = ((const uint4*)b)[lane];
  acc = dot2(a4.x, b4.x, acc); acc = dot2(a4.y, b4.y, acc);
  acc = dot2(a4.z, b4.z, acc); acc = dot2(a4.w, b4.w, acc);
  uint2 a2 = ((const uint2*)(a + 512))[lane];  // elements [512 + lane*4, +4)
  uint2 b2v = ((const uint2*)(b + 512))[lane];
  acc = dot2(a2.x, b2v.x, acc); acc = dot2(a2.y, b2v.y, acc);
#pragma unroll
  for (int off = 32; off >= 1; off >>= 1) acc += __shfl_xor(acc, off);
  if (lane == 0) st[qi] = acc;
}

// ---------------------------------------------------------------------------
// Kernel 3: MFMA GEMM 128x128 tile (BK=64) + fused softmax/rank epilogue.
// 4 waves (2x2), each wave = 4x4 grid of 16x16x32 bf16 MFMAs (64x64).
// LDS is fragment-major: frag f at base f*1024B, lane's 16B at +lane*16 —
// exactly global_load_lds's wave-uniform-base + lane*16 semantics, and
// conflict-free ds_read_b128 (sequential lane addresses).
// A-frag layout: A[m=lane&15][k=quad*8+j]; B^T rows of p load identically.
// C/D layout: col=lane&15, row=quad*4+reg  [m89/m91 verified].
// ---------------------------------------------------------------------------
__global__ __launch_bounds__(256) void gemm_kernel(const unsigned short* __restrict__ qb,
                                                   const unsigned short* __restrict__ pb,
                                                   const float* __restrict__ st,
                                                   float* __restrict__ pm,
                                                   float* __restrict__ pl,
                                                   float* __restrict__ pc) {
  __shared__ unsigned short As[2 * 8 * 512];   // [ks][mt] frags, 16 KB
  __shared__ unsigned short Bs[2 * 8 * 512];   // 16 KB
  __shared__ float st_lds[BM];

  const int t = threadIdx.x;
  const int lane = t & 63;
  const int wv = t >> 6;
  const int wvm = wv >> 1, wvn = wv & 1;
  const int nb = blockIdx.x, mb = blockIdx.y;
  const int qbase = mb * BM;
  const int n0 = nb * BN;
  const int lm = lane & 15;   // row within 16-frag
  const int lq = lane >> 4;   // quad

  if (t < BM) st_lds[t] = st[qbase + t];

  floatx4 acc[4][4];
#pragma unroll
  for (int i = 0; i < 4; ++i)
#pragma unroll
    for (int j = 0; j < 4; ++j) acc[i][j] = (floatx4){0.f, 0.f, 0.f, 0.f};

  for (int kt = 0; kt < KITERS; ++kt) {
    __syncthreads();   // previous compute done (also publishes st_lds at kt=0)
    // stage 32 fragments (A:16, B:16), 8 per wave, 1 KB each
#pragma unroll
    for (int u = 0; u < 8; ++u) {
      const int f = wv * 8 + u;
      const int isB = f >> 4;
      const int fl = f & 15;
      const int ks = fl >> 3;
      const int mt = fl & 7;
      const int row = (isB ? n0 : qbase) + mt * 16 + lm;
      const unsigned short* g = (isB ? pb : qb) + (size_t)row * DD + kt * BK + ks * 32 + lq * 8;
      unsigned short* l = (isB ? Bs : As) + (ks * 8 + mt) * 512;
      __builtin_amdgcn_global_load_lds((const __attribute__((address_space(1))) void*)g,
                                       (__attribute__((address_space(3))) void*)l,
                                       16, 0, 0);
    }
    __syncthreads();   // drains vmcnt(0)
#pragma unroll
    for (int ks = 0; ks < 2; ++ks) {
      short8 a[4], b[4];
#pragma unroll
      for (int i = 0; i < 4; ++i)
        a[i] = *(const short8*)(As + (ks * 8 + wvm * 4 + i) * 512 + lane * 8);
#pragma unroll
      for (int j = 0; j < 4; ++j)
        b[j] = *(const short8*)(Bs + (ks * 8 + wvn * 4 + j) * 512 + lane * 8);
#pragma unroll
      for (int i = 0; i < 4; ++i)
#pragma unroll
        for (int j = 0; j < 4; ++j)
          acc[i][j] = __builtin_amdgcn_mfma_f32_16x16x32_bf16(a[i], b[j], acc[i][j], 0, 0, 0);
    }
  }

  // ---- fused epilogue: per-row (query) max / sumexp / count over 128 cols ----
#pragma unroll
  for (int i = 0; i < 4; ++i) {
#pragma unroll
    for (int r = 0; r < 4; ++r) {
      const int rl = wvm * 64 + i * 16 + lq * 4 + r;   // local query row
      float mx = fmaxf(fmaxf(acc[i][0][r], acc[i][1][r]),
                       fmaxf(acc[i][2][r], acc[i][3][r]));
#pragma unroll
      for (int off = 1; off <= 8; off <<= 1) mx = fmaxf(mx, __shfl_xor(mx, off));
      const float stv = st_lds[rl];
      const int qg = qbase + rl;
      const int tcol = qg * NPASS;
      float sum = 0.f, c = 0.f;
#pragma unroll
      for (int j = 0; j < 4; ++j) {
        const float s = acc[i][j][r];
        sum += __expf(s - mx);
        const int cg = n0 + wvn * 64 + j * 16 + lm;
        if (s > stv && cg != tcol) c += 1.f;
      }
#pragma unroll
      for (int off = 1; off <= 8; off <<= 1) {
        sum += __shfl_xor(sum, off);
        c += __shfl_xor(c, off);
      }
      if (lm == 0) {
        const int chunk = nb * 2 + wvn;
        const size_t idx = (size_t)qg * NCHUNKS + chunk;
        pm[idx] = mx; pl[idx] = sum; pc[idx] = c;
      }
    }
  }
}

// ---------------------------------------------------------------------------
// Kernel 4: merge 256 chunks/query, weighted CE, mean -> atomicAdd. 1 wave/query.
// ---------------------------------------------------------------------------
__global__ __launch_bounds__(256) void finalize_kernel(const float* __restrict__ st,
                                                       const float* __restrict__ pm,
                                                       const float* __restrict__ pl,
                                                       const float* __restrict__ pc,
                                                       float* __restrict__ out) {
  const int wv = threadIdx.x >> 6, lane = threadIdx.x & 63;
  const int qi = blockIdx.x * 4 + wv;
  float4 m4 = ((const float4*)(pm + (size_t)qi * NCHUNKS))[lane];
  float mx = fmaxf(fmaxf(m4.x, m4.y), fmaxf(m4.z, m4.w));
#pragma unroll
  for (int off = 32; off >= 1; off >>= 1) mx = fmaxf(mx, __shfl_xor(mx, off));
  float4 l4 = ((const float4*)(pl + (size_t)qi * NCHUNKS))[lane];
  float4 c4 = ((const float4*)(pc + (size_t)qi * NCHUNKS))[lane];
  float l = l4.x * __expf(m4.x - mx) + l4.y * __expf(m4.y - mx) +
            l4.z * __expf(m4.z - mx) + l4.w * __expf(m4.w - mx);
  float c = c4.x + c4.y + c4.z + c4.w;
#pragma unroll
  for (int off = 32; off >= 1; off >>= 1) {
    l += __shfl_xor(l, off);
    c += __shfl_xor(c, off);
  }
  float loss = 0.f;
  if (lane == 0) {
    const float raw = logf(l) + mx - st[qi];   // -log_softmax[target]
    const float dr = c - 1.0f;                 // rank - OPTIMAL_RANK
    const float w = 1.0f + ALPHA_C * __expf(-(dr * dr) * INV_2SIG2);
    loss = raw * w * (1.0f / (float)BQ);
  }
  __shared__ float red[4];
  if (lane == 0) red[wv] = loss;
  __syncthreads();
  if (threadIdx.x == 0) atomicAdd(out, red[0] + red[1] + red[2] + red[3]);
}

// ---------------------------------------------------------------------------
extern "C" void kernel_launch(void* const* d_in, const int* in_sizes, int n_in,
                              void* d_out, int out_size, void* d_ws, size_t ws_size,
                              hipStream_t stream) {
  const float* q = (const float*)d_in[0];
  const float* p = (const float*)d_in[1];
  char* ws = (char*)d_ws;
  unsigned short* qb = (unsigned short*)ws;                 // 3,145,728 B
  unsigned short* pb = (unsigned short*)(ws + 3145728);     // 25,165,824 B
  float* st = (float*)(ws + 28311552);                      // 8 KB
  float* pm = (float*)(ws + 28319744);                      // 2 MB
  float* pl = (float*)(ws + 30416896);                      // 2 MB
  float* pc = (float*)(ws + 32514048);                      // 2 MB (end ~34.6 MB)
  float* out = (float*)d_out;

  hipMemsetAsync(out, 0, sizeof(float), stream);  // d_out poisoned 0xAA

  cast_kernel<<<NTOT4 / 256, 256, 0, stream>>>((const float4*)q, (const float4*)p,
                                               (uint2*)qb, (uint2*)pb);
  st_kernel<<<BQ / 4, 256, 0, stream>>>(qb, pb, st);
  dim3 g(NBLK, MBLK);
  gemm_kernel<<<g, 256, 0, stream>>>(qb, pb, st, pm, pl, pc);
  finalize_kernel<<<BQ / 4, 256, 0, stream>>>(st, pm, pl, pc, out);
}

// Round 3
// 201.653 us; speedup vs baseline: 15.7551x; 1.1151x over previous
//
#include <hip/hip_runtime.h>
#include <math.h>

// Problem: scores = q[2048x768] @ p[16384x768]^T (fp32 in), per-query
// rank-of-target + log-softmax CE + Gaussian rank weight -> mean (scalar).
// R3: 256x256 tiles (16 waves), BK=96, XCD-swizzled grid so each XCD's
// qb tile stays L2-resident; staging traffic 786->402 MB (L3-BW-bound fix).

#define BQ 2048
#define DD 768
#define NPASS 8
#define PP 16384
#define BM 256
#define BN 256
#define BK 96
#define KITERS 8           // 768/96
#define NBLK 64            // PP/BN
#define MBLK 8             // BQ/BM
#define NCHUNKS 256        // NBLK * 4 n-waves

#define ALPHA_C 2.6f
#define INV_2SIG2 (1.0f/6.48f)   // 1/(2*1.8^2)

typedef __attribute__((ext_vector_type(8))) short short8;   // 8 bf16 (4 VGPRs)
typedef __attribute__((ext_vector_type(4))) float floatx4;  // MFMA C/D

__device__ __forceinline__ unsigned short f2b(float f) {  // fp32 -> bf16 RNE
  union { float f; unsigned u; } c; c.f = f;
  unsigned u = c.u;
  return (unsigned short)((u + 0x7fffu + ((u >> 16) & 1u)) >> 16);
}
__device__ __forceinline__ float b2f(unsigned short b) {
  union { unsigned u; float f; } c; c.u = ((unsigned)b) << 16;
  return c.f;
}
__device__ __forceinline__ float dot2(unsigned ua, unsigned ub, float acc) {
  acc = fmaf(b2f((unsigned short)(ua & 0xffffu)), b2f((unsigned short)(ub & 0xffffu)), acc);
  acc = fmaf(b2f((unsigned short)(ua >> 16)), b2f((unsigned short)(ub >> 16)), acc);
  return acc;
}

// ---------------------------------------------------------------------------
// Kernel 1: cast q and p to bf16 (float4 in, 4 bf16 out)
// ---------------------------------------------------------------------------
#define NQ4   393216     // 2048*768/4
#define NTOT4 3538944    // (2048+16384)*768/4
__global__ __launch_bounds__(256) void cast_kernel(const float4* __restrict__ q,
                                                   const float4* __restrict__ p,
                                                   uint2* __restrict__ qb,
                                                   uint2* __restrict__ pb) {
  int i = blockIdx.x * 256 + threadIdx.x;
  float4 v; uint2* o;
  if (i < NQ4) { v = q[i]; o = qb + i; }
  else         { v = p[i - NQ4]; o = pb + (i - NQ4); }
  uint2 w;
  w.x = (unsigned)f2b(v.x) | ((unsigned)f2b(v.y) << 16);
  w.y = (unsigned)f2b(v.z) | ((unsigned)f2b(v.w) << 16);
  *o = w;
}

// ---------------------------------------------------------------------------
// Kernel 2: s_t[i] = dot(qb[i], pb[i*NPASS]) in fp32 (bf16 inputs) — 1 wave/query
// ---------------------------------------------------------------------------
__global__ __launch_bounds__(256) void st_kernel(const unsigned short* __restrict__ qb,
                                                 const unsigned short* __restrict__ pb,
                                                 float* __restrict__ st) {
  const int wv = threadIdx.x >> 6, lane = threadIdx.x & 63;
  const int qi = blockIdx.x * 4 + wv;
  const unsigned short* a = qb + (size_t)qi * DD;
  const unsigned short* b = pb + (size_t)qi * NPASS * DD;
  float acc = 0.f;
  uint4 a4 = ((const uint4*)a)[lane];
  uint4 b4 = ((const uint4*)b)[lane];
  acc = dot2(a4.x, b4.x, acc); acc = dot2(a4.y, b4.y, acc);
  acc = dot2(a4.z, b4.z, acc); acc = dot2(a4.w, b4.w, acc);
  uint2 a2 = ((const uint2*)(a + 512))[lane];
  uint2 b2v = ((const uint2*)(b + 512))[lane];
  acc = dot2(a2.x, b2v.x, acc); acc = dot2(a2.y, b2v.y, acc);
#pragma unroll
  for (int off = 32; off >= 1; off >>= 1) acc += __shfl_xor(acc, off);
  if (lane == 0) st[qi] = acc;
}

// ---------------------------------------------------------------------------
// Kernel 3: MFMA GEMM 256x256 tile (BK=96) + fused softmax/rank epilogue.
// 16 waves (4x4 grid), each wave 4x4 MFMAs of 16x16x32 bf16 (64x64 out).
// LDS fragment-major: frag f at f*1024B, lane's 16B at +lane*16 — matches
// global_load_lds wave-uniform-base + lane*16, conflict-free ds_read_b128.
// A-frag: A[m=lane&15][k=(lane>>4)*8+j]; C/D: col=lane&15, row=(lane>>4)*4+reg.
// Grid swizzle: mb = bid&7 -> one m-tile per XCD (qb tile L2-resident).
// ---------------------------------------------------------------------------
__global__ __launch_bounds__(1024) void gemm_kernel(const unsigned short* __restrict__ qb,
                                                    const unsigned short* __restrict__ pb,
                                                    const float* __restrict__ st,
                                                    float* __restrict__ pm,
                                                    float* __restrict__ pl,
                                                    float* __restrict__ pc) {
  __shared__ unsigned short As[48 * 512];   // [ks(3)][mt(16)] frags, 48 KB
  __shared__ unsigned short Bs[48 * 512];   // 48 KB
  __shared__ float st_lds[BM];

  const int t = threadIdx.x;
  const int lane = t & 63;
  const int wv = t >> 6;            // 0..15
  const int wm = wv >> 2, wn = wv & 3;
  const int bid = blockIdx.x;
  const int mb = bid & 7;           // XCD round-robin: one mb per XCD
  const int nb = bid >> 3;
  const int qbase = mb * BM;
  const int n0 = nb * BN;
  const int lm = lane & 15;
  const int lq = lane >> 4;

  if (t < BM) st_lds[t] = st[qbase + t];

  floatx4 acc[4][4];
#pragma unroll
  for (int i = 0; i < 4; ++i)
#pragma unroll
    for (int j = 0; j < 4; ++j) acc[i][j] = (floatx4){0.f, 0.f, 0.f, 0.f};

  for (int kt = 0; kt < KITERS; ++kt) {
    __syncthreads();   // prev compute done (also publishes st_lds at kt=0)
    // stage 96 frags (A:48, B:48), 6 per wave, 1 KB each
#pragma unroll
    for (int u = 0; u < 6; ++u) {
      const int f = wv * 6 + u;       // wave-uniform
      const int isB = (f >= 48);
      const int fl = isB ? (f - 48) : f;
      const int ks = fl >> 4;
      const int mt = fl & 15;
      const int row = (isB ? n0 : qbase) + mt * 16 + lm;
      const unsigned short* g = (isB ? pb : qb) + (size_t)row * DD + kt * BK + ks * 32 + lq * 8;
      unsigned short* l = (isB ? Bs : As) + fl * 512;
      __builtin_amdgcn_global_load_lds((const __attribute__((address_space(1))) void*)g,
                                       (__attribute__((address_space(3))) void*)l,
                                       16, 0, 0);
    }
    __syncthreads();   // drains vmcnt(0)
#pragma unroll
    for (int ks = 0; ks < 3; ++ks) {
      short8 a[4], b[4];
#pragma unroll
      for (int i = 0; i < 4; ++i)
        a[i] = *(const short8*)(As + (ks * 16 + wm * 4 + i) * 512 + lane * 8);
#pragma unroll
      for (int j = 0; j < 4; ++j)
        b[j] = *(const short8*)(Bs + (ks * 16 + wn * 4 + j) * 512 + lane * 8);
#pragma unroll
      for (int i = 0; i < 4; ++i)
#pragma unroll
        for (int j = 0; j < 4; ++j)
          acc[i][j] = __builtin_amdgcn_mfma_f32_16x16x32_bf16(a[i], b[j], acc[i][j], 0, 0, 0);
    }
  }

  // ---- fused epilogue: per-row (query) max / sumexp / count over 64 cols ----
#pragma unroll
  for (int i = 0; i < 4; ++i) {
#pragma unroll
    for (int r = 0; r < 4; ++r) {
      const int rl = wm * 64 + i * 16 + lq * 4 + r;   // local query row
      float mx = fmaxf(fmaxf(acc[i][0][r], acc[i][1][r]),
                       fmaxf(acc[i][2][r], acc[i][3][r]));
#pragma unroll
      for (int off = 1; off <= 8; off <<= 1) mx = fmaxf(mx, __shfl_xor(mx, off));
      const float stv = st_lds[rl];
      const int qg = qbase + rl;
      const int tcol = qg * NPASS;
      float sum = 0.f, c = 0.f;
#pragma unroll
      for (int j = 0; j < 4; ++j) {
        const float s = acc[i][j][r];
        sum += __expf(s - mx);
        const int cg = n0 + wn * 64 + j * 16 + lm;
        if (s > stv && cg != tcol) c += 1.f;
      }
#pragma unroll
      for (int off = 1; off <= 8; off <<= 1) {
        sum += __shfl_xor(sum, off);
        c += __shfl_xor(c, off);
      }
      if (lm == 0) {
        const int chunk = nb * 4 + wn;
        const size_t idx = (size_t)qg * NCHUNKS + chunk;
        pm[idx] = mx; pl[idx] = sum; pc[idx] = c;
      }
    }
  }
}

// ---------------------------------------------------------------------------
// Kernel 4: merge 256 chunks/query, weighted CE, mean -> atomicAdd. 1 wave/query.
// ---------------------------------------------------------------------------
__global__ __launch_bounds__(256) void finalize_kernel(const float* __restrict__ st,
                                                       const float* __restrict__ pm,
                                                       const float* __restrict__ pl,
                                                       const float* __restrict__ pc,
                                                       float* __restrict__ out) {
  const int wv = threadIdx.x >> 6, lane = threadIdx.x & 63;
  const int qi = blockIdx.x * 4 + wv;
  float4 m4 = ((const float4*)(pm + (size_t)qi * NCHUNKS))[lane];
  float mx = fmaxf(fmaxf(m4.x, m4.y), fmaxf(m4.z, m4.w));
#pragma unroll
  for (int off = 32; off >= 1; off >>= 1) mx = fmaxf(mx, __shfl_xor(mx, off));
  float4 l4 = ((const float4*)(pl + (size_t)qi * NCHUNKS))[lane];
  float4 c4 = ((const float4*)(pc + (size_t)qi * NCHUNKS))[lane];
  float l = l4.x * __expf(m4.x - mx) + l4.y * __expf(m4.y - mx) +
            l4.z * __expf(m4.z - mx) + l4.w * __expf(m4.w - mx);
  float c = c4.x + c4.y + c4.z + c4.w;
#pragma unroll
  for (int off = 32; off >= 1; off >>= 1) {
    l += __shfl_xor(l, off);
    c += __shfl_xor(c, off);
  }
  float loss = 0.f;
  if (lane == 0) {
    const float raw = logf(l) + mx - st[qi];   // -log_softmax[target]
    const float dr = c - 1.0f;                 // rank - OPTIMAL_RANK
    const float w = 1.0f + ALPHA_C * __expf(-(dr * dr) * INV_2SIG2);
    loss = raw * w * (1.0f / (float)BQ);
  }
  __shared__ float red[4];
  if (lane == 0) red[wv] = loss;
  __syncthreads();
  if (threadIdx.x == 0) atomicAdd(out, red[0] + red[1] + red[2] + red[3]);
}

// ---------------------------------------------------------------------------
extern "C" void kernel_launch(void* const* d_in, const int* in_sizes, int n_in,
                              void* d_out, int out_size, void* d_ws, size_t ws_size,
                              hipStream_t stream) {
  const float* q = (const float*)d_in[0];
  const float* p = (const float*)d_in[1];
  char* ws = (char*)d_ws;
  unsigned short* qb = (unsigned short*)ws;                 // 3,145,728 B
  unsigned short* pb = (unsigned short*)(ws + 3145728);     // 25,165,824 B
  float* st = (float*)(ws + 28311552);                      // 8 KB
  float* pm = (float*)(ws + 28319744);                      // 2 MB
  float* pl = (float*)(ws + 30416896);                      // 2 MB
  float* pc = (float*)(ws + 32514048);                      // 2 MB (end ~34.6 MB)
  float* out = (float*)d_out;

  hipMemsetAsync(out, 0, sizeof(float), stream);  // d_out poisoned 0xAA

  cast_kernel<<<NTOT4 / 256, 256, 0, stream>>>((const float4*)q, (const float4*)p,
                                               (uint2*)qb, (uint2*)pb);
  st_kernel<<<BQ / 4, 256, 0, stream>>>(qb, pb, st);
  gemm_kernel<<<NBLK * MBLK, 1024, 0, stream>>>(qb, pb, st, pm, pl, pc);
  finalize_kernel<<<BQ / 4, 256, 0, stream>>>(st, pm, pl, pc, out);
}